// Round 4
// baseline (567.056 us; speedup 1.0000x reference)
//
#include <hip/hip_runtime.h>
#include <hip/hip_bf16.h>
#include <stdint.h>

typedef __hip_bfloat16 bf16;
typedef __bf16 bf16x8 __attribute__((ext_vector_type(8)));
typedef float floatx4 __attribute__((ext_vector_type(4)));

#define MFMA16(a, b, c) __builtin_amdgcn_mfma_f32_16x16x32_bf16((a), (b), (c), 0, 0, 0)

// fp32 -> bf16 round-to-nearest-even
__device__ __forceinline__ unsigned short f2bf_rne(float f) {
    union { float f; unsigned u; } v; v.f = f;
    const unsigned u = v.u;
    return (unsigned short)((u + 0x7FFFu + ((u >> 16) & 1u)) >> 16);
}

// ---------------------------------------------------------------------------
// GEMM: C[m,n] = sum_k A[m,k] * W[n,k] + bias[n]   (torch Linear, W^T input)
// A: fp32 (AFP32=1) or bf16 (AFP32=0), row-major [M,1024].
// W: fp32 [1024,1024] row-major; bias fp32.
// C: bf16 (CFP32=0) or fp32 (CFP32=1)  <-- final output buffer is FP32!
// 128x128 tile, BK=64, 256 thr = 4 waves (2x2 of 64x64), mfma 16x16x32 bf16.
// LDS pitch 72 (144 B): worst 2-way read conflict (free, m136).
// blockIdx.y: which weight = y>>3, n-tile = y&7.
// ---------------------------------------------------------------------------
template <int AFP32, int CFP32>
__global__ __launch_bounds__(256, 2) void gemm_bt3(
    const void* __restrict__ Av,
    const float* __restrict__ W0, const float* __restrict__ W1, const float* __restrict__ W2,
    const float* __restrict__ b0, const float* __restrict__ b1, const float* __restrict__ b2,
    void* __restrict__ C0, void* __restrict__ C1, void* __restrict__ C2)
{
    __shared__ bf16 As[128 * 72];
    __shared__ bf16 Bs[128 * 72];

    const int tid = threadIdx.x;
    const int which = blockIdx.y >> 3;
    const int nt = blockIdx.y & 7;
    const float* __restrict__ W  = (which == 0) ? W0 : ((which == 1) ? W1 : W2);
    const float* __restrict__ bb = (which == 0) ? b0 : ((which == 1) ? b1 : b2);
    void* __restrict__ C         = (which == 0) ? C0 : ((which == 1) ? C1 : C2);

    const int m0 = blockIdx.x * 128;
    const int n0 = nt * 128;

    const int w  = tid >> 6;
    const int l  = tid & 63;
    const int lr = l & 15;          // frag row within 16
    const int q  = l >> 4;          // quad
    const int wm = (w & 1) * 64;
    const int wn = (w >> 1) * 64;

    floatx4 acc[4][4];
#pragma unroll
    for (int i = 0; i < 4; ++i)
#pragma unroll
        for (int j = 0; j < 4; ++j)
            acc[i][j] = (floatx4){0.f, 0.f, 0.f, 0.f};

#pragma unroll 1
    for (int kt = 0; kt < 16; ++kt) {
        __syncthreads();
        // stage A-tile and W-tile: 128 rows x 64 k, 8-elem chunks
#pragma unroll
        for (int ct = 0; ct < 4; ++ct) {
            const int c   = ct * 256 + tid;
            const int row = c >> 3;
            const int kg  = c & 7;
            const long koff = (long)kt * 64 + kg * 8;
            unsigned short o[8];
            if (AFP32) {
                const float* Ap = (const float*)Av + (long)(m0 + row) * 1024 + koff;
                const uint4 lo = *(const uint4*)(Ap);
                const uint4 hi = *(const uint4*)(Ap + 4);
                const float* fl = (const float*)&lo;
                const float* fh = (const float*)&hi;
#pragma unroll
                for (int e = 0; e < 4; ++e) o[e] = f2bf_rne(fl[e]);
#pragma unroll
                for (int e = 0; e < 4; ++e) o[4 + e] = f2bf_rne(fh[e]);
            } else {
                const uint4 d = *(const uint4*)((const bf16*)Av +
                                 (long)(m0 + row) * 1024 + koff);
                *(uint4*)o = d;
            }
            *(uint4*)(As + row * 72 + kg * 8) = *(const uint4*)o;

            const float* Wp = W + (long)(n0 + row) * 1024 + koff;
            const uint4 wlo = *(const uint4*)(Wp);
            const uint4 whi = *(const uint4*)(Wp + 4);
            const float* wl = (const float*)&wlo;
            const float* wh = (const float*)&whi;
#pragma unroll
            for (int e = 0; e < 4; ++e) o[e] = f2bf_rne(wl[e]);
#pragma unroll
            for (int e = 0; e < 4; ++e) o[4 + e] = f2bf_rne(wh[e]);
            *(uint4*)(Bs + row * 72 + kg * 8) = *(const uint4*)o;
        }
        __syncthreads();

#pragma unroll
        for (int ks = 0; ks < 2; ++ks) {
            bf16x8 av[4], bv[4];
#pragma unroll
            for (int i = 0; i < 4; ++i)
                av[i] = *(const bf16x8*)(As + (wm + i * 16 + lr) * 72 + ks * 32 + q * 8);
#pragma unroll
            for (int j = 0; j < 4; ++j)
                bv[j] = *(const bf16x8*)(Bs + (wn + j * 16 + lr) * 72 + ks * 32 + q * 8);
#pragma unroll
            for (int i = 0; i < 4; ++i)
#pragma unroll
                for (int j = 0; j < 4; ++j)
                    acc[i][j] = MFMA16(av[i], bv[j], acc[i][j]);
        }
    }

    // epilogue: C/D layout col = lane&15, row = quad*4 + reg
#pragma unroll
    for (int j = 0; j < 4; ++j) {
        const int col = n0 + wn + j * 16 + lr;
        const float bj = bb[col];
#pragma unroll
        for (int i = 0; i < 4; ++i) {
#pragma unroll
            for (int r = 0; r < 4; ++r) {
                const int row = m0 + wm + i * 16 + q * 4 + r;
                const float val = acc[i][j][r] + bj;
                if (CFP32)
                    ((float*)C)[(long)row * 1024 + col] = val;
                else
                    ((unsigned short*)C)[(long)row * 1024 + col] = f2bf_rne(val);
            }
        }
    }
}

// ---------------------------------------------------------------------------
// Flash attention forward. Q,K,V: [B=4, n=2048, H=16, dk=64] bf16 (dk contig).
// 256 thr / 4 waves; one (b,h), 128 Q rows; 32 key-tiles of 64:
// S = Q K^T, online softmax (exp2 domain), P -> LDS (C->A layout),
// O += P V with V transposed in LDS. Output AO same layout, bf16.
// ---------------------------------------------------------------------------
__global__ __launch_bounds__(256, 2) void attn_flash(
    const bf16* __restrict__ Q, const bf16* __restrict__ K, const bf16* __restrict__ V,
    bf16* __restrict__ AO)
{
    __shared__ bf16 Qs[128 * 72];
    __shared__ bf16 Ks[64 * 72];
    __shared__ bf16 Ps[128 * 72];
    __shared__ bf16 Vt[64 * 72];   // Vt[dk][key]

    const int tid = threadIdx.x;
    const int b = blockIdx.y >> 4, h = blockIdx.y & 15;
    const int q0 = blockIdx.x * 128;
    const size_t base = ((size_t)b * 2048) * 1024 + (size_t)h * 64;

    const int w  = tid >> 6;
    const int l  = tid & 63;
    const int lr = l & 15;
    const int q  = l >> 4;

    // preload Q tile (128 x 64)
#pragma unroll
    for (int r = 0; r < 4; ++r) {
        const int u = r * 256 + tid;
        const int row = u >> 3, kg = u & 7;
        uint4 d = *(const uint4*)(Q + base + (size_t)(q0 + row) * 1024 + kg * 8);
        *(uint4*)(Qs + row * 72 + kg * 8) = d;
    }

    floatx4 O[2][4];
    float mprev[2][4], lsum[2][4];
#pragma unroll
    for (int i = 0; i < 2; ++i) {
#pragma unroll
        for (int d = 0; d < 4; ++d) O[i][d] = (floatx4){0.f, 0.f, 0.f, 0.f};
#pragma unroll
        for (int r = 0; r < 4; ++r) { mprev[i][r] = -1e30f; lsum[i][r] = 0.f; }
    }
    const float cs = 0.18033688011112042f;  // log2(e) / sqrt(64)

#pragma unroll 1
    for (int kt = 0; kt < 32; ++kt) {
        __syncthreads();
        // stage K tile (64x64) and V tile transposed
#pragma unroll
        for (int r = 0; r < 2; ++r) {
            const int u = r * 256 + tid;
            const int row = u >> 3, kg = u & 7;
            const size_t goff = base + (size_t)(kt * 64 + row) * 1024 + kg * 8;
            uint4 kd = *(const uint4*)(K + goff);
            *(uint4*)(Ks + row * 72 + kg * 8) = kd;
            uint4 vd = *(const uint4*)(V + goff);
            const unsigned short* vs = (const unsigned short*)&vd;
#pragma unroll
            for (int d2 = 0; d2 < 8; ++d2)
                ((unsigned short*)Vt)[(kg * 8 + d2) * 72 + row] = vs[d2];
        }
        __syncthreads();

        // S = Q K^T for this wave's 32 rows x 64 keys
        floatx4 s[2][4];
#pragma unroll
        for (int i = 0; i < 2; ++i)
#pragma unroll
            for (int t = 0; t < 4; ++t)
                s[i][t] = (floatx4){0.f, 0.f, 0.f, 0.f};
#pragma unroll
        for (int ks = 0; ks < 2; ++ks) {
            bf16x8 qa[2], kb[4];
#pragma unroll
            for (int i = 0; i < 2; ++i)
                qa[i] = *(const bf16x8*)(Qs + (w * 32 + i * 16 + lr) * 72 + ks * 32 + q * 8);
#pragma unroll
            for (int t = 0; t < 4; ++t)
                kb[t] = *(const bf16x8*)(Ks + (t * 16 + lr) * 72 + ks * 32 + q * 8);
#pragma unroll
            for (int i = 0; i < 2; ++i)
#pragma unroll
                for (int t = 0; t < 4; ++t)
                    s[i][t] = MFMA16(qa[i], kb[t], s[i][t]);
        }

        // online softmax; row r of block i lives at (reg r, quad q),
        // cols spread over lane&15 and the 4 col-tiles t
#pragma unroll
        for (int i = 0; i < 2; ++i) {
#pragma unroll
            for (int r = 0; r < 4; ++r) {
                float v = fmaxf(fmaxf(s[i][0][r], s[i][1][r]),
                                fmaxf(s[i][2][r], s[i][3][r]));
                v = fmaxf(v, __shfl_xor(v, 1));
                v = fmaxf(v, __shfl_xor(v, 2));
                v = fmaxf(v, __shfl_xor(v, 4));
                v = fmaxf(v, __shfl_xor(v, 8));
                const float mc = v * cs;
                const float mnew  = fmaxf(mprev[i][r], mc);
                const float alpha = exp2f(mprev[i][r] - mnew);
                float rsum = 0.f;
#pragma unroll
                for (int t = 0; t < 4; ++t) {
                    const float p = exp2f(s[i][t][r] * cs - mnew);
                    s[i][t][r] = p;
                    rsum += p;
                }
                rsum += __shfl_xor(rsum, 1);
                rsum += __shfl_xor(rsum, 2);
                rsum += __shfl_xor(rsum, 4);
                rsum += __shfl_xor(rsum, 8);
                lsum[i][r] = lsum[i][r] * alpha + rsum;
                mprev[i][r] = mnew;
#pragma unroll
                for (int d = 0; d < 4; ++d) O[i][d][r] *= alpha;
            }
        }

        // P (C-layout) -> LDS, own wave's rows only
#pragma unroll
        for (int i = 0; i < 2; ++i)
#pragma unroll
            for (int t = 0; t < 4; ++t)
#pragma unroll
                for (int r = 0; r < 4; ++r)
                    ((unsigned short*)Ps)[(w * 32 + i * 16 + q * 4 + r) * 72 + t * 16 + lr] =
                        f2bf_rne(s[i][t][r]);
        asm volatile("s_waitcnt lgkmcnt(0)" ::: "memory");

        // O += P V
#pragma unroll
        for (int kc = 0; kc < 2; ++kc) {
            bf16x8 pa[2], vb[4];
#pragma unroll
            for (int i = 0; i < 2; ++i)
                pa[i] = *(const bf16x8*)(Ps + (w * 32 + i * 16 + lr) * 72 + kc * 32 + q * 8);
#pragma unroll
            for (int d = 0; d < 4; ++d)
                vb[d] = *(const bf16x8*)(Vt + (d * 16 + lr) * 72 + kc * 32 + q * 8);
#pragma unroll
            for (int i = 0; i < 2; ++i)
#pragma unroll
                for (int d = 0; d < 4; ++d)
                    O[i][d] = MFMA16(pa[i], vb[d], O[i][d]);
        }
    }

    // normalize and store
#pragma unroll
    for (int i = 0; i < 2; ++i) {
#pragma unroll
        for (int r = 0; r < 4; ++r) {
            const float inv = 1.f / lsum[i][r];
            const int row = q0 + w * 32 + i * 16 + q * 4 + r;
#pragma unroll
            for (int d = 0; d < 4; ++d)
                ((unsigned short*)AO)[base + (size_t)row * 1024 + d * 16 + lr] =
                    f2bf_rne(O[i][d][r] * inv);
        }
    }
}

extern "C" void kernel_launch(void* const* d_in, const int* in_sizes, int n_in,
                              void* d_out, int out_size, void* d_ws, size_t ws_size,
                              hipStream_t stream) {
    (void)in_sizes; (void)n_in; (void)out_size; (void)ws_size;
    const float* X  = (const float*)d_in[0];
    const float* Wq = (const float*)d_in[1];
    const float* bq = (const float*)d_in[2];
    const float* Wk = (const float*)d_in[3];
    const float* bk = (const float*)d_in[4];
    const float* Wv = (const float*)d_in[5];
    const float* bv = (const float*)d_in[6];
    const float* Wo = (const float*)d_in[7];
    const float* bo = (const float*)d_in[8];
    float* out = (float*)d_out;   // OUTPUT IS FP32 (reference returns float32)

    // workspace: 4 x 16 MiB bf16 buffers = 64 MiB
    const size_t SZ = (size_t)8192 * 1024;
    bf16* Qb  = (bf16*)d_ws;
    bf16* Kb  = Qb + SZ;
    bf16* Vb  = Kb + SZ;
    bf16* AOb = Vb + SZ;

    // 1) fused QKV projection (A = X fp32 converted inline; C = bf16)
    gemm_bt3<1, 0><<<dim3(64, 24), dim3(256), 0, stream>>>(
        (const void*)X, Wq, Wk, Wv, bq, bk, bv,
        (void*)Qb, (void*)Kb, (void*)Vb);

    // 2) flash attention
    attn_flash<<<dim3(16, 64), dim3(256), 0, stream>>>(Qb, Kb, Vb, AOb);

    // 3) output projection (A = AO bf16; C = fp32 final output)
    gemm_bt3<0, 1><<<dim3(64, 8), dim3(256), 0, stream>>>(
        (const void*)AOb, Wo, Wo, Wo, bo, bo, bo,
        (void*)out, (void*)out, (void*)out);
}

// Round 5
// 466.284 us; speedup vs baseline: 1.2161x; 1.2161x over previous
//
#include <hip/hip_runtime.h>
#include <hip/hip_bf16.h>
#include <stdint.h>

typedef __hip_bfloat16 bf16;
typedef __bf16 bf16x8 __attribute__((ext_vector_type(8)));
typedef float floatx4 __attribute__((ext_vector_type(4)));
typedef unsigned short u16x8 __attribute__((ext_vector_type(8)));

#define MFMA16(a, b, c) __builtin_amdgcn_mfma_f32_16x16x32_bf16((a), (b), (c), 0, 0, 0)

typedef __attribute__((address_space(3))) uint32_t lds_u32;
typedef const __attribute__((address_space(1))) uint32_t gbl_u32;

__device__ __forceinline__ void async16(const void* g, void* s) {
    __builtin_amdgcn_global_load_lds((gbl_u32*)g, (lds_u32*)s, 16, 0, 0);
}

// fp32 -> bf16 round-to-nearest-even
__device__ __forceinline__ unsigned short f2bf_rne(float f) {
    union { float f; unsigned u; } v; v.f = f;
    const unsigned u = v.u;
    return (unsigned short)((u + 0x7FFFu + ((u >> 16) & 1u)) >> 16);
}

// ---------------------------------------------------------------------------
// arena element offsets: X 8M | Wq 1M | Wk 1M | Wv 1M | Wo 1M  (bf16)
// ---------------------------------------------------------------------------
#define A_X   0L
#define A_WQ  8388608L
#define A_WK  9437184L
#define A_WV  10485760L
#define A_WO  11534336L
#define A_END 12582912L

// one-time fp32 -> bf16 conversion of X + 4 weight matrices into the arena
__global__ __launch_bounds__(256) void cvt5(
    const float* __restrict__ s0, const float* __restrict__ s1,
    const float* __restrict__ s2, const float* __restrict__ s3,
    const float* __restrict__ s4, unsigned short* __restrict__ dst)
{
    const long beg[6] = {A_X, A_WQ, A_WK, A_WV, A_WO, A_END};
    const float* srcs[5] = {s0, s1, s2, s3, s4};
    const long nchunk = A_END / 8;
    for (long c = (long)blockIdx.x * 256 + threadIdx.x; c < nchunk;
         c += (long)gridDim.x * 256) {
        const long off = c * 8;
        int s = 0;
#pragma unroll
        for (int i = 1; i < 5; ++i) if (off >= beg[i]) s = i;
        const float* sp = srcs[s] + (off - beg[s]);
        const uint4 lo = *(const uint4*)(sp);
        const uint4 hi = *(const uint4*)(sp + 4);
        const float* fl = (const float*)&lo;
        const float* fh = (const float*)&hi;
        unsigned short o[8];
#pragma unroll
        for (int e = 0; e < 4; ++e) o[e] = f2bf_rne(fl[e]);
#pragma unroll
        for (int e = 0; e < 4; ++e) o[4 + e] = f2bf_rne(fh[e]);
        *(uint4*)(dst + off) = *(const uint4*)o;
    }
}

// ---------------------------------------------------------------------------
// GEMM (m97 ladder structure): C[m,n] = sum_k A[m,k]*W[n,k] + bias[n]
// A, W bf16 row-major [.,1024]; bias fp32; C bf16 (CFP32=0) or fp32 (CFP32=1).
// 128x128 tile, BK=64, 4 waves, global_load_lds 16B, XOR k-group swizzle.
// R2/R3 bit-identical absmax proved this staging correct.
// ---------------------------------------------------------------------------
template <int CFP32>
__global__ __launch_bounds__(256, 2) void gemm_bt3(
    const bf16* __restrict__ A,
    const bf16* __restrict__ W0, const bf16* __restrict__ W1, const bf16* __restrict__ W2,
    const float* __restrict__ b0, const float* __restrict__ b1, const float* __restrict__ b2,
    void* __restrict__ C0, void* __restrict__ C1, void* __restrict__ C2)
{
    __shared__ bf16 As[128 * 64];
    __shared__ bf16 Bs[128 * 64];

    const int tid = threadIdx.x;
    const int which = blockIdx.y >> 3;
    const int nt = blockIdx.y & 7;
    const bf16* __restrict__ W   = (which == 0) ? W0 : ((which == 1) ? W1 : W2);
    const float* __restrict__ bb = (which == 0) ? b0 : ((which == 1) ? b1 : b2);
    void* __restrict__ C         = (which == 0) ? C0 : ((which == 1) ? C1 : C2);

    const int m0 = blockIdx.x * 128;
    const int n0 = nt * 128;

    const int w  = tid >> 6;
    const int l  = tid & 63;
    const int lr = l & 15;
    const int q  = l >> 4;
    const int wm = (w & 1) * 64;
    const int wn = (w >> 1) * 64;
    const int wbase = tid & 0xC0;

    floatx4 acc[4][4];
#pragma unroll
    for (int i = 0; i < 4; ++i)
#pragma unroll
        for (int j = 0; j < 4; ++j)
            acc[i][j] = (floatx4){0.f, 0.f, 0.f, 0.f};

#pragma unroll 1
    for (int kt = 0; kt < 16; ++kt) {
        __syncthreads();
#pragma unroll
        for (int r = 0; r < 4; ++r) {
            const int u   = r * 256 + tid;
            const int row = u >> 3;
            const int kg  = u & 7;
            const int kgg = kg ^ (row & 7);   // XOR swizzle on global side
            const size_t goffA = (size_t)(m0 + row) * 1024 + kt * 64 + kgg * 8;
            const size_t goffB = (size_t)(n0 + row) * 1024 + kt * 64 + kgg * 8;
            bf16* dA = As + (size_t)(r * 256 + wbase) * 8;   // wave-uniform base
            bf16* dB = Bs + (size_t)(r * 256 + wbase) * 8;
            async16(A + goffA, dA);
            async16(W + goffB, dB);
        }
        asm volatile("s_waitcnt vmcnt(0)" ::: "memory");
        __syncthreads();

#pragma unroll
        for (int ks = 0; ks < 2; ++ks) {
            bf16x8 av[4], bv[4];
#pragma unroll
            for (int i = 0; i < 4; ++i) {
                const int row = wm + i * 16 + lr;
                const int kg  = (ks * 4 + q) ^ (row & 7);
                av[i] = *(const bf16x8*)(As + row * 64 + kg * 8);
            }
#pragma unroll
            for (int j = 0; j < 4; ++j) {
                const int row = wn + j * 16 + lr;
                const int kg  = (ks * 4 + q) ^ (row & 7);
                bv[j] = *(const bf16x8*)(Bs + row * 64 + kg * 8);
            }
#pragma unroll
            for (int i = 0; i < 4; ++i)
#pragma unroll
                for (int j = 0; j < 4; ++j)
                    acc[i][j] = MFMA16(av[i], bv[j], acc[i][j]);
        }
    }

    // epilogue: C/D layout col = lane&15, row = quad*4 + reg
#pragma unroll
    for (int j = 0; j < 4; ++j) {
        const int col = n0 + wn + j * 16 + lr;
        const float bj = bb[col];
#pragma unroll
        for (int i = 0; i < 4; ++i) {
#pragma unroll
            for (int r = 0; r < 4; ++r) {
                const int row = m0 + wm + i * 16 + q * 4 + r;
                const float val = acc[i][j][r] + bj;
                if (CFP32)
                    ((float*)C)[(long)row * 1024 + col] = val;
                else
                    ((unsigned short*)C)[(long)row * 1024 + col] = f2bf_rne(val);
            }
        }
    }
}

// ---------------------------------------------------------------------------
// Flash attention. Q,K,V: [B=4, n=2048, H=16, dk=64] bf16.
// 4 waves, 128 Q rows/block, 32 key-tiles of 64.
// R5: double-buffered K/V with register prefetch (1 barrier/iter);
//     V transposed via coalesced u16 column loads + ds_write_b128 (kills the
//     8-way scatter conflicts); Ps octet-XOR swizzle (4-way -> 2-way free).
// ---------------------------------------------------------------------------
__global__ __launch_bounds__(256, 2) void attn_flash(
    const bf16* __restrict__ Q, const bf16* __restrict__ K, const bf16* __restrict__ V,
    bf16* __restrict__ AO)
{
    __shared__ bf16 Qs[128 * 72];
    __shared__ bf16 Ps[128 * 72];
    __shared__ bf16 Ks[2][64 * 72];
    __shared__ bf16 Vt[2][64 * 72];   // Vt[dk][key]

    const int tid = threadIdx.x;
    const int b = blockIdx.y >> 4, h = blockIdx.y & 15;
    const int q0 = blockIdx.x * 128;
    const size_t base = ((size_t)b * 2048) * 1024 + (size_t)h * 64;

    const int w  = tid >> 6;
    const int l  = tid & 63;
    const int lr = l & 15;
    const int q  = l >> 4;

    // staging geometry (constant across iterations)
    const int krow = tid >> 3;        // 0..31 (two row-halves per iter)
    const int kkg  = tid & 7;
    const int vd   = tid & 63;        // dk index (equals lane)
    const int vo   = tid >> 6;        // key-octet 0..3 (+4 for second half)

    const unsigned short* __restrict__ Vg = (const unsigned short*)V;

    // Q preload (128 x 64)
#pragma unroll
    for (int r = 0; r < 4; ++r) {
        const int u = r * 256 + tid;
        const int row = u >> 3, kg = u & 7;
        uint4 d = *(const uint4*)(Q + base + (size_t)(q0 + row) * 1024 + kg * 8);
        *(uint4*)(Qs + row * 72 + kg * 8) = d;
    }

    // prefetch tile 0 into registers
    uint4 kreg0, kreg1;
    u16x8 vregA, vregB;
    {
        kreg0 = *(const uint4*)(K + base + (size_t)(krow) * 1024 + kkg * 8);
        kreg1 = *(const uint4*)(K + base + (size_t)(32 + krow) * 1024 + kkg * 8);
#pragma unroll
        for (int j = 0; j < 8; ++j)
            vregA[j] = Vg[base + (size_t)(vo * 8 + j) * 1024 + vd];
#pragma unroll
        for (int j = 0; j < 8; ++j)
            vregB[j] = Vg[base + (size_t)(32 + vo * 8 + j) * 1024 + vd];
    }

    floatx4 O[2][4];
    float mprev[2][4], lsum[2][4];
#pragma unroll
    for (int i = 0; i < 2; ++i) {
#pragma unroll
        for (int d = 0; d < 4; ++d) O[i][d] = (floatx4){0.f, 0.f, 0.f, 0.f};
#pragma unroll
        for (int r = 0; r < 4; ++r) { mprev[i][r] = -1e30f; lsum[i][r] = 0.f; }
    }
    const float cs = 0.18033688011112042f;  // log2(e) / sqrt(64)

#pragma unroll 1
    for (int kt = 0; kt < 32; ++kt) {
        bf16* KsB = Ks[kt & 1];
        bf16* VtB = Vt[kt & 1];

        // write prefetched tile to LDS (compiler inserts vmcnt wait)
        *(uint4*)(KsB + krow * 72 + kkg * 8)        = kreg0;
        *(uint4*)(KsB + (32 + krow) * 72 + kkg * 8) = kreg1;
        *(uint4*)(VtB + vd * 72 + vo * 8)           = *(const uint4*)&vregA;
        *(uint4*)(VtB + vd * 72 + 32 + vo * 8)      = *(const uint4*)&vregB;
        __syncthreads();

        // prefetch next tile
        if (kt < 31) {
            const size_t kb = base + (size_t)((kt + 1) * 64) * 1024;
            kreg0 = *(const uint4*)(K + kb + (size_t)(krow) * 1024 + kkg * 8);
            kreg1 = *(const uint4*)(K + kb + (size_t)(32 + krow) * 1024 + kkg * 8);
#pragma unroll
            for (int j = 0; j < 8; ++j)
                vregA[j] = Vg[kb + (size_t)(vo * 8 + j) * 1024 + vd];
#pragma unroll
            for (int j = 0; j < 8; ++j)
                vregB[j] = Vg[kb + (size_t)(32 + vo * 8 + j) * 1024 + vd];
        }

        // S = Q K^T (this wave's 32 rows x 64 keys)
        floatx4 s[2][4];
#pragma unroll
        for (int i = 0; i < 2; ++i)
#pragma unroll
            for (int t = 0; t < 4; ++t)
                s[i][t] = (floatx4){0.f, 0.f, 0.f, 0.f};
#pragma unroll
        for (int ks = 0; ks < 2; ++ks) {
            bf16x8 qa[2], kb[4];
#pragma unroll
            for (int i = 0; i < 2; ++i)
                qa[i] = *(const bf16x8*)(Qs + (w * 32 + i * 16 + lr) * 72 + ks * 32 + q * 8);
#pragma unroll
            for (int t = 0; t < 4; ++t)
                kb[t] = *(const bf16x8*)(KsB + (t * 16 + lr) * 72 + ks * 32 + q * 8);
#pragma unroll
            for (int i = 0; i < 2; ++i)
#pragma unroll
                for (int t = 0; t < 4; ++t)
                    s[i][t] = MFMA16(qa[i], kb[t], s[i][t]);
        }

        // online softmax (exp2 domain)
#pragma unroll
        for (int i = 0; i < 2; ++i) {
#pragma unroll
            for (int r = 0; r < 4; ++r) {
                float v = fmaxf(fmaxf(s[i][0][r], s[i][1][r]),
                                fmaxf(s[i][2][r], s[i][3][r]));
                v = fmaxf(v, __shfl_xor(v, 1));
                v = fmaxf(v, __shfl_xor(v, 2));
                v = fmaxf(v, __shfl_xor(v, 4));
                v = fmaxf(v, __shfl_xor(v, 8));
                const float mc = v * cs;
                const float mnew  = fmaxf(mprev[i][r], mc);
                const float alpha = exp2f(mprev[i][r] - mnew);
                float rsum = 0.f;
#pragma unroll
                for (int t = 0; t < 4; ++t) {
                    const float p = exp2f(s[i][t][r] * cs - mnew);
                    s[i][t][r] = p;
                    rsum += p;
                }
                rsum += __shfl_xor(rsum, 1);
                rsum += __shfl_xor(rsum, 2);
                rsum += __shfl_xor(rsum, 4);
                rsum += __shfl_xor(rsum, 8);
                lsum[i][r] = lsum[i][r] * alpha + rsum;
                mprev[i][r] = mnew;
#pragma unroll
                for (int d = 0; d < 4; ++d) O[i][d][r] *= alpha;
            }
        }

        // P (C-layout) -> LDS with octet-XOR swizzle: slot = (key>>3)^((row>>2)&3)
        // write row = w*32+i*16+q*4+r -> (row>>2)&3 = q; key = t*16+lr
#pragma unroll
        for (int i = 0; i < 2; ++i)
#pragma unroll
            for (int t = 0; t < 4; ++t)
#pragma unroll
                for (int r = 0; r < 4; ++r)
                    ((unsigned short*)Ps)[(w * 32 + i * 16 + q * 4 + r) * 72 +
                        (((t * 2 + (lr >> 3)) ^ q) * 8) + (lr & 7)] =
                        f2bf_rne(s[i][t][r]);
        asm volatile("s_waitcnt lgkmcnt(0)" ::: "memory");

        // O += P V   (read row = w*32+i*16+lr -> (row>>2)&3 = (lr>>2)&3)
#pragma unroll
        for (int kc = 0; kc < 2; ++kc) {
            bf16x8 pa[2], vb[4];
#pragma unroll
            for (int i = 0; i < 2; ++i)
                pa[i] = *(const bf16x8*)(Ps + (w * 32 + i * 16 + lr) * 72 +
                         (kc * 4 + (q ^ ((lr >> 2) & 3))) * 8);
#pragma unroll
            for (int d = 0; d < 4; ++d)
                vb[d] = *(const bf16x8*)(VtB + (d * 16 + lr) * 72 + kc * 32 + q * 8);
#pragma unroll
            for (int i = 0; i < 2; ++i)
#pragma unroll
                for (int d = 0; d < 4; ++d)
                    O[i][d] = MFMA16(pa[i], vb[d], O[i][d]);
        }
    }

    // normalize and store
#pragma unroll
    for (int i = 0; i < 2; ++i) {
#pragma unroll
        for (int r = 0; r < 4; ++r) {
            const float inv = 1.f / lsum[i][r];
            const int row = q0 + w * 32 + i * 16 + q * 4 + r;
#pragma unroll
            for (int d = 0; d < 4; ++d)
                ((unsigned short*)AO)[base + (size_t)row * 1024 + d * 16 + lr] =
                    f2bf_rne(O[i][d][r] * inv);
        }
    }
}

extern "C" void kernel_launch(void* const* d_in, const int* in_sizes, int n_in,
                              void* d_out, int out_size, void* d_ws, size_t ws_size,
                              hipStream_t stream) {
    (void)in_sizes; (void)n_in; (void)out_size; (void)ws_size;
    const float* X  = (const float*)d_in[0];
    const float* Wq = (const float*)d_in[1];
    const float* bq = (const float*)d_in[2];
    const float* Wk = (const float*)d_in[3];
    const float* bk = (const float*)d_in[4];
    const float* Wv = (const float*)d_in[5];
    const float* bv = (const float*)d_in[6];
    const float* Wo = (const float*)d_in[7];
    const float* bo = (const float*)d_in[8];
    float* out = (float*)d_out;   // output is fp32

    // ws: bf16 arena (24 MiB) + Q/K/V/AO (4 x 16 MiB) = 88 MiB
    unsigned short* arena = (unsigned short*)d_ws;
    bf16* Xb  = (bf16*)(arena + A_X);
    bf16* Wqb = (bf16*)(arena + A_WQ);
    bf16* Wkb = (bf16*)(arena + A_WK);
    bf16* Wvb = (bf16*)(arena + A_WV);
    bf16* Wob = (bf16*)(arena + A_WO);

    const size_t SZ = (size_t)8192 * 1024;
    bf16* Qb  = (bf16*)(arena + A_END);
    bf16* Kb  = Qb + SZ;
    bf16* Vb  = Kb + SZ;
    bf16* AOb = Vb + SZ;

    // 0) one-time fp32 -> bf16 of X and the four weight matrices
    cvt5<<<dim3(1536), dim3(256), 0, stream>>>(X, Wq, Wk, Wv, Wo, arena);

    // 1) fused QKV projection (bf16 arena, global_load_lds staging)
    gemm_bt3<0><<<dim3(64, 24), dim3(256), 0, stream>>>(
        Xb, Wqb, Wkb, Wvb, bq, bk, bv, (void*)Qb, (void*)Kb, (void*)Vb);

    // 2) flash attention
    attn_flash<<<dim3(16, 64), dim3(256), 0, stream>>>(Qb, Kb, Vb, AOb);

    // 3) output projection -> fp32 d_out
    gemm_bt3<1><<<dim3(64, 8), dim3(256), 0, stream>>>(
        AOb, Wob, Wob, Wob, bo, bo, bo, (void*)out, (void*)out, (void*)out);
}

// Round 6
// 382.773 us; speedup vs baseline: 1.4814x; 1.2182x over previous
//
#include <hip/hip_runtime.h>
#include <hip/hip_bf16.h>
#include <stdint.h>

typedef __hip_bfloat16 bf16;
typedef __bf16 bf16x8 __attribute__((ext_vector_type(8)));
typedef float floatx4 __attribute__((ext_vector_type(4)));
typedef unsigned short u16x8 __attribute__((ext_vector_type(8)));

#define MFMA16(a, b, c) __builtin_amdgcn_mfma_f32_16x16x32_bf16((a), (b), (c), 0, 0, 0)

typedef __attribute__((address_space(3))) uint32_t lds_u32;
typedef const __attribute__((address_space(1))) uint32_t gbl_u32;

__device__ __forceinline__ void async16(const void* g, void* s) {
    __builtin_amdgcn_global_load_lds((gbl_u32*)g, (lds_u32*)s, 16, 0, 0);
}

// fp32 -> bf16 round-to-nearest-even
__device__ __forceinline__ unsigned short f2bf_rne(float f) {
    union { float f; unsigned u; } v; v.f = f;
    const unsigned u = v.u;
    return (unsigned short)((u + 0x7FFFu + ((u >> 16) & 1u)) >> 16);
}

// ---------------------------------------------------------------------------
// arena element offsets: X 8M | Wq 1M | Wk 1M | Wv 1M | Wo 1M  (bf16)
// ---------------------------------------------------------------------------
#define A_X   0L
#define A_WQ  8388608L
#define A_WK  9437184L
#define A_WV  10485760L
#define A_WO  11534336L
#define A_END 12582912L

__global__ __launch_bounds__(256) void cvt5(
    const float* __restrict__ s0, const float* __restrict__ s1,
    const float* __restrict__ s2, const float* __restrict__ s3,
    const float* __restrict__ s4, unsigned short* __restrict__ dst)
{
    const long beg[6] = {A_X, A_WQ, A_WK, A_WV, A_WO, A_END};
    const float* srcs[5] = {s0, s1, s2, s3, s4};
    const long nchunk = A_END / 8;
    for (long c = (long)blockIdx.x * 256 + threadIdx.x; c < nchunk;
         c += (long)gridDim.x * 256) {
        const long off = c * 8;
        int s = 0;
#pragma unroll
        for (int i = 1; i < 5; ++i) if (off >= beg[i]) s = i;
        const float* sp = srcs[s] + (off - beg[s]);
        const uint4 lo = *(const uint4*)(sp);
        const uint4 hi = *(const uint4*)(sp + 4);
        const float* fl = (const float*)&lo;
        const float* fh = (const float*)&hi;
        unsigned short o[8];
#pragma unroll
        for (int e = 0; e < 4; ++e) o[e] = f2bf_rne(fl[e]);
#pragma unroll
        for (int e = 0; e < 4; ++e) o[4 + e] = f2bf_rne(fh[e]);
        *(uint4*)(dst + off) = *(const uint4*)o;
    }
}

// ---------------------------------------------------------------------------
// GEMM (m97 structure, validated R4/R5): C = A W^T + b
// ---------------------------------------------------------------------------
template <int CFP32>
__global__ __launch_bounds__(256, 2) void gemm_bt3(
    const bf16* __restrict__ A,
    const bf16* __restrict__ W0, const bf16* __restrict__ W1, const bf16* __restrict__ W2,
    const float* __restrict__ b0, const float* __restrict__ b1, const float* __restrict__ b2,
    void* __restrict__ C0, void* __restrict__ C1, void* __restrict__ C2)
{
    __shared__ bf16 As[128 * 64];
    __shared__ bf16 Bs[128 * 64];

    const int tid = threadIdx.x;
    const int which = blockIdx.y >> 3;
    const int nt = blockIdx.y & 7;
    const bf16* __restrict__ W   = (which == 0) ? W0 : ((which == 1) ? W1 : W2);
    const float* __restrict__ bb = (which == 0) ? b0 : ((which == 1) ? b1 : b2);
    void* __restrict__ C         = (which == 0) ? C0 : ((which == 1) ? C1 : C2);

    const int m0 = blockIdx.x * 128;
    const int n0 = nt * 128;

    const int w  = tid >> 6;
    const int l  = tid & 63;
    const int lr = l & 15;
    const int q  = l >> 4;
    const int wm = (w & 1) * 64;
    const int wn = (w >> 1) * 64;
    const int wbase = tid & 0xC0;

    floatx4 acc[4][4];
#pragma unroll
    for (int i = 0; i < 4; ++i)
#pragma unroll
        for (int j = 0; j < 4; ++j)
            acc[i][j] = (floatx4){0.f, 0.f, 0.f, 0.f};

#pragma unroll 1
    for (int kt = 0; kt < 16; ++kt) {
        __syncthreads();
#pragma unroll
        for (int r = 0; r < 4; ++r) {
            const int u   = r * 256 + tid;
            const int row = u >> 3;
            const int kg  = u & 7;
            const int kgg = kg ^ (row & 7);
            const size_t goffA = (size_t)(m0 + row) * 1024 + kt * 64 + kgg * 8;
            const size_t goffB = (size_t)(n0 + row) * 1024 + kt * 64 + kgg * 8;
            bf16* dA = As + (size_t)(r * 256 + wbase) * 8;
            bf16* dB = Bs + (size_t)(r * 256 + wbase) * 8;
            async16(A + goffA, dA);
            async16(W + goffB, dB);
        }
        asm volatile("s_waitcnt vmcnt(0)" ::: "memory");
        __syncthreads();

#pragma unroll
        for (int ks = 0; ks < 2; ++ks) {
            bf16x8 av[4], bv[4];
#pragma unroll
            for (int i = 0; i < 4; ++i) {
                const int row = wm + i * 16 + lr;
                const int kg  = (ks * 4 + q) ^ (row & 7);
                av[i] = *(const bf16x8*)(As + row * 64 + kg * 8);
            }
#pragma unroll
            for (int j = 0; j < 4; ++j) {
                const int row = wn + j * 16 + lr;
                const int kg  = (ks * 4 + q) ^ (row & 7);
                bv[j] = *(const bf16x8*)(Bs + row * 64 + kg * 8);
            }
#pragma unroll
            for (int i = 0; i < 4; ++i)
#pragma unroll
                for (int j = 0; j < 4; ++j)
                    acc[i][j] = MFMA16(av[i], bv[j], acc[i][j]);
        }
    }

#pragma unroll
    for (int j = 0; j < 4; ++j) {
        const int col = n0 + wn + j * 16 + lr;
        const float bj = bb[col];
#pragma unroll
        for (int i = 0; i < 4; ++i) {
#pragma unroll
            for (int r = 0; r < 4; ++r) {
                const int row = m0 + wm + i * 16 + q * 4 + r;
                const float val = acc[i][j][r] + bj;
                if (CFP32)
                    ((float*)C)[(long)row * 1024 + col] = val;
                else
                    ((unsigned short*)C)[(long)row * 1024 + col] = f2bf_rne(val);
            }
        }
    }
}

// ---------------------------------------------------------------------------
// Flash attention, S^T formulation. Q,K,V: [4,2048,16,64] bf16.
// S^T = K Q^T  (A=K, B=Q-in-regs): lane holds col=qrow(lane&15), row=key(q*4+r)
//   -> softmax state (m,l) is ONE row per lane; reductions = in-lane + 2 shfl.
// P written row-contiguous (b64), read as B-frag (b128).
// O^T = V^T P^T (A=Vt, B=Ps): col=qrow, row=d -> no alpha broadcast needed.
// LDS 40KB (Ks/Vt dbuf pitch-64 XOR-swizzled, Ps 16KB) -> 4 blocks/CU.
// ---------------------------------------------------------------------------
__global__ __launch_bounds__(256, 4) void attn_flash(
    const bf16* __restrict__ Q, const bf16* __restrict__ K, const bf16* __restrict__ V,
    bf16* __restrict__ AO)
{
    __shared__ bf16 Ks[2][64 * 64];
    __shared__ bf16 Vt[2][64 * 64];   // Vt[d][key]
    __shared__ bf16 Ps[128 * 64];     // P[qrow][key], octet-swizzled

    const int tid = threadIdx.x;
    const int b = blockIdx.y >> 4, h = blockIdx.y & 15;
    const int q0 = blockIdx.x * 128;
    const size_t base = ((size_t)b * 2048) * 1024 + (size_t)h * 64;

    const int w  = tid >> 6;
    const int l  = tid & 63;
    const int lr = l & 15;
    const int q  = l >> 4;

    const int krow = tid >> 3, kkg = tid & 7;   // K staging geometry
    const int vd = tid & 63,   vo = tid >> 6;   // V staging geometry
    const unsigned short* __restrict__ Vg = (const unsigned short*)V;

    // Q fragments in registers (reused all 32 iterations): B-frag layout
    bf16x8 qb[2][2];
#pragma unroll
    for (int i = 0; i < 2; ++i)
#pragma unroll
        for (int ks = 0; ks < 2; ++ks)
            qb[i][ks] = *(const bf16x8*)(Q + base +
                (size_t)(q0 + w * 32 + i * 16 + lr) * 1024 + ks * 32 + q * 8);

    // prefetch tile 0
    uint4 kreg0 = *(const uint4*)(K + base + (size_t)krow * 1024 + kkg * 8);
    uint4 kreg1 = *(const uint4*)(K + base + (size_t)(32 + krow) * 1024 + kkg * 8);
    u16x8 vregA, vregB;
#pragma unroll
    for (int j = 0; j < 8; ++j)
        vregA[j] = Vg[base + (size_t)(vo * 8 + j) * 1024 + vd];
#pragma unroll
    for (int j = 0; j < 8; ++j)
        vregB[j] = Vg[base + (size_t)(32 + vo * 8 + j) * 1024 + vd];

    floatx4 O[2][4];
#pragma unroll
    for (int i = 0; i < 2; ++i)
#pragma unroll
        for (int d = 0; d < 4; ++d) O[i][d] = (floatx4){0.f, 0.f, 0.f, 0.f};
    float mprev[2] = {-1e30f, -1e30f}, lsum[2] = {0.f, 0.f};
    const float cs = 0.18033688011112042f;  // log2(e)/sqrt(64)

#pragma unroll 1
    for (int kt = 0; kt < 32; ++kt) {
        bf16* KsB = Ks[kt & 1];
        bf16* VtB = Vt[kt & 1];

        // stage prefetched K/V tile (XOR-octet swizzle, pitch 64)
        *(uint4*)(KsB + krow * 64 + (kkg ^ (krow & 7)) * 8)        = kreg0;
        *(uint4*)(KsB + (32 + krow) * 64 + (kkg ^ (krow & 7)) * 8) = kreg1;
        *(uint4*)(VtB + vd * 64 + (vo ^ (vd & 7)) * 8)             = *(const uint4*)&vregA;
        *(uint4*)(VtB + vd * 64 + ((4 + vo) ^ (vd & 7)) * 8)       = *(const uint4*)&vregB;
        __syncthreads();

        if (kt < 31) {
            const size_t kb = base + (size_t)((kt + 1) * 64) * 1024;
            kreg0 = *(const uint4*)(K + kb + (size_t)krow * 1024 + kkg * 8);
            kreg1 = *(const uint4*)(K + kb + (size_t)(32 + krow) * 1024 + kkg * 8);
#pragma unroll
            for (int j = 0; j < 8; ++j)
                vregA[j] = Vg[kb + (size_t)(vo * 8 + j) * 1024 + vd];
#pragma unroll
            for (int j = 0; j < 8; ++j)
                vregB[j] = Vg[kb + (size_t)(32 + vo * 8 + j) * 1024 + vd];
        }

        // S^T = K Q^T : s[i][t], lane: col=qrow lr, row=key q*4+r (tile 16t)
        floatx4 s[2][4];
#pragma unroll
        for (int i = 0; i < 2; ++i)
#pragma unroll
            for (int t = 0; t < 4; ++t)
                s[i][t] = (floatx4){0.f, 0.f, 0.f, 0.f};
#pragma unroll
        for (int ks = 0; ks < 2; ++ks) {
            bf16x8 kb[4];
#pragma unroll
            for (int t = 0; t < 4; ++t) {
                const int R = t * 16 + lr;
                kb[t] = *(const bf16x8*)(KsB + R * 64 + (((ks * 4 + q) ^ (R & 7)) * 8));
            }
#pragma unroll
            for (int i = 0; i < 2; ++i)
#pragma unroll
                for (int t = 0; t < 4; ++t)
                    s[i][t] = MFMA16(kb[t], qb[i][ks], s[i][t]);
        }

        // online softmax: one qrow per lane per i
#pragma unroll
        for (int i = 0; i < 2; ++i) {
            float vm = fmaxf(fmaxf(s[i][0][0], s[i][0][1]), fmaxf(s[i][0][2], s[i][0][3]));
#pragma unroll
            for (int t = 1; t < 4; ++t)
                vm = fmaxf(vm, fmaxf(fmaxf(s[i][t][0], s[i][t][1]),
                                     fmaxf(s[i][t][2], s[i][t][3])));
            vm = fmaxf(vm, __shfl_xor(vm, 16));
            vm = fmaxf(vm, __shfl_xor(vm, 32));
            const float mnew  = fmaxf(mprev[i], vm * cs);
            const float alpha = exp2f(mprev[i] - mnew);
            mprev[i] = mnew;
            float rsum = 0.f;
#pragma unroll
            for (int t = 0; t < 4; ++t)
#pragma unroll
                for (int r = 0; r < 4; ++r) {
                    const float p = exp2f(s[i][t][r] * cs - mnew);
                    s[i][t][r] = p;
                    rsum += p;
                }
            rsum += __shfl_xor(rsum, 16);
            rsum += __shfl_xor(rsum, 32);
            lsum[i] = lsum[i] * alpha + rsum;
#pragma unroll
            for (int d = 0; d < 4; ++d) O[i][d] *= alpha;

            // P -> Ps[qrow][key] (b64, contiguous keys 16t+4q..+3), swizzled
            const int R = w * 32 + i * 16 + lr;
#pragma unroll
            for (int t = 0; t < 4; ++t) {
                unsigned short hh[4];
#pragma unroll
                for (int r = 0; r < 4; ++r) hh[r] = f2bf_rne(s[i][t][r]);
                *(uint2*)((unsigned short*)Ps + R * 64 +
                          (((2 * t + (q >> 1)) ^ (R & 7)) * 8) + (q & 1) * 4) =
                    *(const uint2*)hh;
            }
        }
        asm volatile("s_waitcnt lgkmcnt(0)" ::: "memory");

        // O^T += V^T P^T : A=Vt frag, B=Ps frag
#pragma unroll
        for (int kc = 0; kc < 2; ++kc) {
            bf16x8 va[4], pb[2];
#pragma unroll
            for (int dt = 0; dt < 4; ++dt) {
                const int R = dt * 16 + lr;
                va[dt] = *(const bf16x8*)(VtB + R * 64 + (((kc * 4 + q) ^ (R & 7)) * 8));
            }
#pragma unroll
            for (int i = 0; i < 2; ++i) {
                const int R = w * 32 + i * 16 + lr;
                pb[i] = *(const bf16x8*)(Ps + R * 64 + (((kc * 4 + q) ^ (R & 7)) * 8));
            }
#pragma unroll
            for (int i = 0; i < 2; ++i)
#pragma unroll
                for (int dt = 0; dt < 4; ++dt)
                    O[i][dt] = MFMA16(va[dt], pb[i], O[i][dt]);
        }
    }

    // epilogue: lane holds qrow = q0+w*32+i*16+lr, d = dt*16+q*4+r
#pragma unroll
    for (int i = 0; i < 2; ++i) {
        const float inv = 1.f / lsum[i];
        const int row = q0 + w * 32 + i * 16 + lr;
#pragma unroll
        for (int dt = 0; dt < 4; ++dt) {
            unsigned short hh[4];
#pragma unroll
            for (int r = 0; r < 4; ++r) hh[r] = f2bf_rne(O[i][dt][r] * inv);
            *(uint2*)((unsigned short*)AO + base + (size_t)row * 1024 +
                      dt * 16 + q * 4) = *(const uint2*)hh;
        }
    }
}

extern "C" void kernel_launch(void* const* d_in, const int* in_sizes, int n_in,
                              void* d_out, int out_size, void* d_ws, size_t ws_size,
                              hipStream_t stream) {
    (void)in_sizes; (void)n_in; (void)out_size; (void)ws_size;
    const float* X  = (const float*)d_in[0];
    const float* Wq = (const float*)d_in[1];
    const float* bq = (const float*)d_in[2];
    const float* Wk = (const float*)d_in[3];
    const float* bk = (const float*)d_in[4];
    const float* Wv = (const float*)d_in[5];
    const float* bv = (const float*)d_in[6];
    const float* Wo = (const float*)d_in[7];
    const float* bo = (const float*)d_in[8];
    float* out = (float*)d_out;

    unsigned short* arena = (unsigned short*)d_ws;
    bf16* Xb  = (bf16*)(arena + A_X);
    bf16* Wqb = (bf16*)(arena + A_WQ);
    bf16* Wkb = (bf16*)(arena + A_WK);
    bf16* Wvb = (bf16*)(arena + A_WV);
    bf16* Wob = (bf16*)(arena + A_WO);

    const size_t SZ = (size_t)8192 * 1024;
    bf16* Qb  = (bf16*)(arena + A_END);
    bf16* Kb  = Qb + SZ;
    bf16* Vb  = Kb + SZ;
    bf16* AOb = Vb + SZ;

    cvt5<<<dim3(1536), dim3(256), 0, stream>>>(X, Wq, Wk, Wv, Wo, arena);

    gemm_bt3<0><<<dim3(64, 24), dim3(256), 0, stream>>>(
        Xb, Wqb, Wkb, Wvb, bq, bk, bv, (void*)Qb, (void*)Kb, (void*)Vb);

    attn_flash<<<dim3(16, 64), dim3(256), 0, stream>>>(Qb, Kb, Vb, AOb);

    gemm_bt3<1><<<dim3(64, 8), dim3(256), 0, stream>>>(
        AOb, Wob, Wob, Wob, bo, bo, bo, (void*)out, (void*)out, (void*)out);
}